// Round 2
// baseline (79.061 us; speedup 1.0000x reference)
//
#include <hip/hip_runtime.h>

// SampledSoftmaxLoss: N=51200 rows, D=64, K=100 negatives, V=100001 items.
// loss = sum_n w_n * (logsumexp(logits_n) - pos_logit_n) / sum_n w_n
// logits = cos_sim(vo_n, item_idx) / 0.05
//
// Pass 1 normalizes the item table into an fp8-e4m3 [V][64B] copy in ws
// (6.4 MB -> ~62% L2 hit, misses served by L3).
//
// r8: block-cooperative main pass. Evidence from r5/r7: dur == FETCH/BW with
// BW scaling in wave count (2.62 vs 2.15 TB/s at identical 152 MB) -> the
// gather path is MLP-limited, and per-wave VGPR-held gathers can't deepen
// (7xuint4 dbuf = 56 VGPR -> occupancy cliff at 64, r7 regression).
// New structure: one 256-thread block per row step; the 101 item rows
// (6.5 KB) are staged into LDS via 7 global_load_lds (16B/lane, ZERO VGPR),
// double-buffered; next row's neg-index loads issued in the same shadow.
//   - VGPR ~48 -> 8 waves/SIMD; LDS 17 KB -> 8 blocks/CU; full 32 waves/CU.
//   - In-flight gather bytes per CU ~60-110 KB vs ~3 KB before.
//   - Compute: 4 lanes/item, lane-linear ds_read_b128 (conflict-free),
//     2 passes x 64 slots; shfl chains 10/row (was 19).
//   - s_red/s_pos double-buffered so ONE __syncthreads per row suffices
//     (max intra-block wave skew = 1 row between barriers).

#define D_DIM 64
#define K_NEG 100
#define INV_TEMP 20.0f
#define MAX_LOGIT 20.0f
#define LOG2E 1.4426950408889634f
#define LN2 0.6931471805599453f
#define MAXL2 28.853900817779268f   // MAX_LOGIT * LOG2E

#define NBLK_MAIN 2048
#define NBLK_NORM 512
#define NSLOT 128   // padded item slots (101 staged/used; pad avoids OOB reads)

typedef float fv2 __attribute__((ext_vector_type(2)));

__device__ __forceinline__ void gload_lds16(const void* g, void* l) {
  __builtin_amdgcn_global_load_lds(
      (const __attribute__((address_space(1))) unsigned int*)g,
      (__attribute__((address_space(3))) unsigned int*)l, 16, 0, 0);
}
__device__ __forceinline__ void gload_lds4(const void* g, void* l) {
  __builtin_amdgcn_global_load_lds(
      (const __attribute__((address_space(1))) unsigned int*)g,
      (__attribute__((address_space(3))) unsigned int*)l, 4, 0, 0);
}

// ---------------- Pass 1: normalize item table -> fp8 e4m3 ----------------
__global__ __launch_bounds__(256) void normalize_kernel(
    const float* __restrict__ items, unsigned int* __restrict__ tab, int V) {
  const int lane = threadIdx.x & 63;
  const int wid  = threadIdx.x >> 6;
  const int g = lane >> 4, q = lane & 15;
  const int waveId = blockIdx.x * 4 + wid;
  const int nWaves = gridDim.x * 4;
  for (int base = waveId * 4; base < V; base += nWaves * 4) {
    const int r = base + g;
    const bool act = (r < V);
    float4 x = make_float4(0.f, 0.f, 0.f, 0.f);
    if (act) x = *reinterpret_cast<const float4*>(items + (size_t)r * D_DIM + q * 4);
    float ss = x.x * x.x + x.y * x.y + x.z * x.z + x.w * x.w;
    ss += __shfl_xor(ss, 1);
    ss += __shfl_xor(ss, 2);
    ss += __shfl_xor(ss, 4);
    ss += __shfl_xor(ss, 8);
    const float inv = 1.0f / fmaxf(sqrtf(ss), 1e-12f);
    if (act) {
      int u = 0;
      u = __builtin_amdgcn_cvt_pk_fp8_f32(x.x * inv, x.y * inv, u, false);
      u = __builtin_amdgcn_cvt_pk_fp8_f32(x.z * inv, x.w * inv, u, true);
      tab[(size_t)r * 16 + q] = (unsigned int)u;
    }
  }
}

// ---------------- Pass 2: main loss (block-cooperative) ----------------
// Block handles rows r = blockIdx.x + k*gridDim.x (25 rows each at 2048).
// Staging (wave-owned global_load_lds insts, 16 item rows per inst):
//   wave w: inst w (slots 16w..16w+15) and inst w+4 (w<=2; inst 6 partial,
//   only slots <= 100). wave 3 additionally stages the query row (4B/lane).
// Compute: item slot s = pass*64 + wid*16 + (lane>>2); lane covers bytes
//   (lane&3)*16 of the item row -> LDS address = base + lane*16 (linear).
__global__ __launch_bounds__(256) void loss_kernel(
    const float* __restrict__ oe,      // [N,64]
    const int*   __restrict__ tgt,     // [N]
    const unsigned int* __restrict__ tab, // [V][16] uints of packed fp8
    const float* __restrict__ wgt,     // [N]
    const int*   __restrict__ negi,    // [N,100]
    const int*   __restrict__ alti,    // [N,100]
    float2*      __restrict__ partials,// [gridDim.x]
    int N) {
  __shared__ uint4 s_items[2][NSLOT * 4];  // 2 x 8192 B
  __shared__ float s_q[2][D_DIM];          // 2 x 256 B
  __shared__ float s_red[2][4];
  __shared__ float s_pos[2];

  const int tid  = threadIdx.x;
  const int lane = tid & 63;
  const int wid  = tid >> 6;
  const int sub  = lane >> 2;   // row-within-inst 0..15
  const int qd   = lane & 3;    // 16B chunk within a 64B item row
  const int G    = gridDim.x;

  const int i1 = wid;           // first owned staging inst
  const int i2 = wid + 4;       // second owned staging inst (wid<=2)
  const int s1 = 16 * i1 + sub; // slot of first inst
  const int s2 = 16 * i2 + sub; // slot of second inst (64..111)
  const bool has2 = (wid <= 2) && (s2 <= K_NEG);

  float num = 0.f, den = 0.f;
  int r = blockIdx.x;

  // idx/scalars for the NEXT row to stage (loaded one iteration ahead)
  int ndB1 = 0, ndB2 = 0, tN = 0;
  float wC = 0.f, wN = 0.f;

  // load raw neg indices for staging row rowS (this wave's slots)
  auto LOADIDX = [&](int rowS, int& d1, int& d2) {
    const int* nr = negi + (size_t)rowS * K_NEG;
    d1 = (s1 > 0) ? __builtin_nontemporal_load(nr + (s1 - 1)) : 0;
    d2 = has2 ? __builtin_nontemporal_load(nr + (s2 - 1)) : 0;
  };

  // resolve collisions and issue this wave's staging for row rowS -> buf nb
  auto STAGE = [&](int rowS, int nb, int d1, int d2, int tS) {
    const int* ar = alti + (size_t)rowS * K_NEG;
    int v1 = (s1 == 0) ? tS : d1;
    if (s1 > 0 && v1 == tS) v1 = ar[s1 - 1];       // rare, execz-skipped
    gload_lds16(tab + (size_t)v1 * 16 + qd * 4, &s_items[nb][64 * i1]);
    if (has2) {
      int v2 = d2;
      if (v2 == tS) v2 = ar[s2 - 1];
      gload_lds16(tab + (size_t)v2 * 16 + qd * 4, &s_items[nb][64 * i2]);
    }
    if (wid == 3) gload_lds4(oe + (size_t)rowS * D_DIM + lane, &s_q[nb][0]);
  };

  // ---- prologue: stage row r into buf 0, load idx for row r+G ----
  if (r < N) {
    int d1, d2;
    LOADIDX(r, d1, d2);
    const int t0 = tgt[r];       // uniform -> scalar load
    wC = wgt[r];
    STAGE(r, 0, d1, d2, t0);
    const int r1 = r + G;
    if (r1 < N) {
      LOADIDX(r1, ndB1, ndB2);
      tN = tgt[r1];
      wN = wgt[r1];
    }
  }
  __syncthreads();

  int cur = 0;
  while (r < N) {
    const int r1 = r + G, r2 = r + 2 * G;
    // 1) issue next row's staging (whole compute phase to land)
    if (r1 < N) STAGE(r1, cur ^ 1, ndB1, ndB2, tN);
    // 2) issue idx loads two rows ahead
    int nd1n = 0, nd2n = 0, tn2 = 0;
    float wn2 = 0.f;
    if (r2 < N) {
      LOADIDX(r2, nd1n, nd2n);
      tn2 = tgt[r2];
      wn2 = wgt[r2];
    }

    // 3) compute row r from buf[cur]
    {
      const float4* qp = reinterpret_cast<const float4*>(&s_q[cur][qd * 16]);
      const float4 x0 = qp[0], x1 = qp[1], x2 = qp[2], x3 = qp[3];
      const fv2 qa0 = {x0.x, x0.y}, qa1 = {x0.z, x0.w};
      const fv2 qa2 = {x1.x, x1.y}, qa3 = {x1.z, x1.w};
      const fv2 qa4 = {x2.x, x2.y}, qa5 = {x2.z, x2.w};
      const fv2 qa6 = {x3.x, x3.y}, qa7 = {x3.z, x3.w};

      // query norm: lane's 16-dim partial; 4 chunks (qd) cover all 64 dims
      fv2 ss2 = qa0 * qa0;
      ss2 += qa1 * qa1;
      ss2 += qa2 * qa2;
      ss2 += qa3 * qa3;
      ss2 += qa4 * qa4;
      ss2 += qa5 * qa5;
      ss2 += qa6 * qa6;
      ss2 += qa7 * qa7;
      float ss = ss2[0] + ss2[1];
      ss += __shfl_xor(ss, 1);
      ss += __shfl_xor(ss, 2);
      const float inv_o = 1.0f / fmaxf(sqrtf(ss), 1e-12f);
      const float scale = inv_o * INV_TEMP;
      const float sc2 = scale * LOG2E;

      float sacc = 0.f;
#pragma unroll
      for (int p = 0; p < 2; ++p) {
        const int s = p * 64 + wid * 16 + sub;       // logit index j
        const uint4 rv = s_items[cur][s * 4 + qd];   // lane-linear ds_read_b128
        fv2 acc;
        acc  = qa0 * __builtin_amdgcn_cvt_pk_f32_fp8((int)rv.x, false);
        acc += qa1 * __builtin_amdgcn_cvt_pk_f32_fp8((int)rv.x, true);
        acc += qa2 * __builtin_amdgcn_cvt_pk_f32_fp8((int)rv.y, false);
        acc += qa3 * __builtin_amdgcn_cvt_pk_f32_fp8((int)rv.y, true);
        acc += qa4 * __builtin_amdgcn_cvt_pk_f32_fp8((int)rv.z, false);
        acc += qa5 * __builtin_amdgcn_cvt_pk_f32_fp8((int)rv.z, true);
        acc += qa6 * __builtin_amdgcn_cvt_pk_f32_fp8((int)rv.w, false);
        acc += qa7 * __builtin_amdgcn_cvt_pk_f32_fp8((int)rv.w, true);
        float d = acc[0] + acc[1];
        d += __shfl_xor(d, 1);
        d += __shfl_xor(d, 2);          // all 4 lanes of the group hold the dot
        if (p == 0 && tid == 0) s_pos[cur] = d * scale;  // slot 0 = positive
        const float e = exp2f(fmaf(d, sc2, -MAXL2));
        sacc += (s <= K_NEG && qd == 0) ? e : 0.f;  // garbage slots masked
      }
      sacc += __shfl_xor(sacc, 4);
      sacc += __shfl_xor(sacc, 8);
      sacc += __shfl_xor(sacc, 16);
      sacc += __shfl_xor(sacc, 32);
      if (lane == 0) s_red[cur][wid] = sacc;
    }

    // 4) one barrier: red/pos visible AND next buf's load_lds drained
    __syncthreads();

    if (tid == 0) {
      const float S = s_red[cur][0] + s_red[cur][1] + s_red[cur][2] + s_red[cur][3];
      const float lse = log2f(S) * LN2 + MAX_LOGIT;
      const float loss = lse - s_pos[cur];
      if (wC > 0.f) {
        num += loss * wC;
        den += wC;
      }
    }

    wC = wN; wN = wn2;
    ndB1 = nd1n; ndB2 = nd2n; tN = tn2;
    cur ^= 1;
    r += G;
  }

  if (tid == 0) partials[blockIdx.x] = make_float2(num, den);
}

// ---------------- Pass 3: final reduce ----------------
__global__ __launch_bounds__(256) void finish_kernel(
    const float2* __restrict__ partials, int nblk, float* __restrict__ out) {
  float num = 0.f, den = 0.f;
  for (int i = threadIdx.x; i < nblk; i += 256) {
    const float2 p = partials[i];
    num += p.x;
    den += p.y;
  }
#pragma unroll
  for (int m = 1; m < 64; m <<= 1) {
    num += __shfl_xor(num, m);
    den += __shfl_xor(den, m);
  }
  __shared__ float2 red[4];
  const int wid = threadIdx.x >> 6;
  const int lane = threadIdx.x & 63;
  if (lane == 0) red[wid] = make_float2(num, den);
  __syncthreads();
  if (threadIdx.x == 0) {
    float n = 0.f, d = 0.f;
#pragma unroll
    for (int i = 0; i < 4; ++i) { n += red[i].x; d += red[i].y; }
    out[0] = n / d;
  }
}

extern "C" void kernel_launch(void* const* d_in, const int* in_sizes, int n_in,
                              void* d_out, int out_size, void* d_ws, size_t ws_size,
                              hipStream_t stream) {
  const float* oe    = (const float*)d_in[0];  // output_embeddings [B,S,64]
  const int*   tgt   = (const int*)  d_in[1];  // target_ids [B,S]
  const float* items = (const float*)d_in[2];  // all_item_embeddings [V,64]
  const float* wgt   = (const float*)d_in[3];  // supervision_weights [B,S]
  const int*   negi  = (const int*)  d_in[4];  // neg_indices [N,100]
  const int*   alti  = (const int*)  d_in[5];  // alt_neg_indices [N,100]

  const int N = in_sizes[0] / D_DIM;  // 51200
  const int V = in_sizes[2] / D_DIM;  // 100001

  unsigned int* tab = (unsigned int*)d_ws;                    // V*16 uints (6.4 MB)
  size_t off = ((size_t)V * 16 * sizeof(unsigned int) + 255) & ~(size_t)255;
  float2* partials = (float2*)((char*)d_ws + off);            // NBLK_MAIN float2

  normalize_kernel<<<NBLK_NORM, 256, 0, stream>>>(items, tab, V);
  loss_kernel<<<NBLK_MAIN, 256, 0, stream>>>(oe, tgt, tab, wgt, negi, alti,
                                             partials, N);
  finish_kernel<<<1, 256, 0, stream>>>(partials, NBLK_MAIN, (float*)d_out);
}